// Round 1
// baseline (381.691 us; speedup 1.0000x reference)
//
#include <hip/hip_runtime.h>

typedef short bf16x8 __attribute__((ext_vector_type(8)));   // 8 bf16 bit-patterns (4 VGPRs)
typedef float f32x4 __attribute__((ext_vector_type(4)));

#define NROWS 131072L
#define DIN 1024
#define DEMB 512

__device__ __forceinline__ unsigned short f2bf(float f) {
  unsigned u = __float_as_uint(f);
  u += 0x7FFFu + ((u >> 16) & 1u);     // RNE
  return (unsigned short)(u >> 16);
}

__device__ __forceinline__ float softplusf(float v) {
  return fmaxf(v, 0.f) + log1pf(expf(-fabsf(v)));
}

// ---------- kernel 0: Wb (1024x512 f32) -> WbT (512x1024 bf16) ----------
__global__ __launch_bounds__(256) void wb_transpose(const float* __restrict__ Wb,
                                                    unsigned short* __restrict__ WbT) {
  int g = blockIdx.x * 256 + threadIdx.x;   // 65536 threads
  int n = g & 511;
  int kb = g >> 9;                          // 0..127, 8 k each
  unsigned short tmp[8];
#pragma unroll
  for (int j = 0; j < 8; ++j)
    tmp[j] = f2bf(Wb[(kb * 8 + j) * DEMB + n]);   // coalesced reads across lanes (n consecutive)
  uint4 v;
  v.x = (unsigned)tmp[0] | ((unsigned)tmp[1] << 16);
  v.y = (unsigned)tmp[2] | ((unsigned)tmp[3] << 16);
  v.z = (unsigned)tmp[4] | ((unsigned)tmp[5] << 16);
  v.w = (unsigned)tmp[6] | ((unsigned)tmp[7] << 16);
  *(uint4*)(WbT + (long)n * DIN + kb * 8) = v;
}

// ---------- kernel 1: emb = bf16MFMA(x @ WbT^T) + bb ----------
// 128x128 tile, BK=64, 4 waves (2x2), each wave 64x64 via 4x4 frags of 16x16x32.
// A: reg-staged f32->bf16 with XOR-swizzled LDS. B: global_load_lds w/ pre-swizzled source.
__global__ __launch_bounds__(256, 2) void gemm_bias(const float* __restrict__ x,
                                                    const unsigned short* __restrict__ wbt,
                                                    const float* __restrict__ bb,
                                                    float* __restrict__ emb) {
  __shared__ unsigned short As[2][128 * 64];
  __shared__ unsigned short Bsh[2][128 * 64];

  const int t = threadIdx.x;
  const int lane = t & 63;
  const int wid = t >> 6;
  const int wm = wid >> 1, wn = wid & 1;

  // XCD-aware swizzle (4096 blocks, 4096%8==0 -> simple bijective form).
  const int bid = blockIdx.x;
  const int swz = (bid & 7) * 512 + (bid >> 3);
  const int ntile = swz & 3;
  const long mtile = swz >> 2;
  const long m0 = mtile * 128;
  const int n0 = ntile * 128;

  // ---- A staging addressing (per thread: 8 passes of float4) ----
  const int arow = t >> 4;                    // 0..15 (+p*16)
  const int acol8 = (t & 15) * 8;             // byte col in row (bits 3-6)
  const int abyte = arow * 128 + (acol8 ^ ((arow & 7) << 4));   // +p*2048
  const float* xbase = x + (m0 + arow) * DIN + (t & 15) * 4;

  // ---- B staging (global_load_lds, pre-swizzled source) ----
  // granule gi = wid*256 + i*64 + lane ; n = gi>>3 ; src granule = (lane&7)^(n&7)
  const int bn = wid * 32 + (lane >> 3);                   // +i*8
  const int bg = (lane & 7) ^ (lane >> 3);                 // swizzled granule in row
  const unsigned short* bsrc = wbt + (long)(n0 + bn) * DIN + bg * 8;

  // ---- fragment read offsets (swizzle applied to full k-granule: (ks*4+lg)^s) ----
  const int l15 = lane & 15, lg = lane >> 4;
  const int s3 = lane & 7;                                  // row&7 for both A and B reads
  const int kg0 = ((lg ^ s3) << 4);                         // ks=0 granule byte; ks=1 -> ^64
  const int ardrow = (wm * 64 + l15) * 128;
  const int brdrow = (wn * 64 + l15) * 128;

  f32x4 acc[4][4] = {};
  float4 areg[8];

  auto loadA = [&](int k0) {
#pragma unroll
    for (int p = 0; p < 8; ++p)
      areg[p] = *(const float4*)(xbase + (long)p * 16 * DIN + k0);
  };
  auto stageB = [&](int b, int k0) {
#pragma unroll
    for (int i = 0; i < 4; ++i) {
      const unsigned short* gp = bsrc + (long)i * 8 * DIN + k0;
      unsigned short* lp = &Bsh[b][(wid * 256 + i * 64) * 8];
      __builtin_amdgcn_global_load_lds(
          (const __attribute__((address_space(1))) void*)gp,
          (__attribute__((address_space(3))) void*)lp, 16, 0, 0);
    }
  };
  auto writeA = [&](int b) {
    char* base = (char*)As[b];
#pragma unroll
    for (int p = 0; p < 8; ++p) {
      ushort4 v;
      v.x = f2bf(areg[p].x); v.y = f2bf(areg[p].y);
      v.z = f2bf(areg[p].z); v.w = f2bf(areg[p].w);
      *(ushort4*)(base + abyte + p * 2048) = v;
    }
  };
  auto compute = [&](int b) {
    const char* Ab = (const char*)As[b];
    const char* Bb = (const char*)Bsh[b];
#pragma unroll
    for (int ks = 0; ks < 2; ++ks) {
      const int kgo = kg0 ^ (ks << 6);
      bf16x8 af[4], bf_[4];
#pragma unroll
      for (int i = 0; i < 4; ++i) {
        af[i] = *(const bf16x8*)(Ab + ardrow + i * 2048 + kgo);
        bf_[i] = *(const bf16x8*)(Bb + brdrow + i * 2048 + kgo);
      }
#pragma unroll
      for (int mi = 0; mi < 4; ++mi)
#pragma unroll
        for (int ni = 0; ni < 4; ++ni)
          acc[mi][ni] = __builtin_amdgcn_mfma_f32_16x16x32_bf16(af[mi], bf_[ni],
                                                               acc[mi][ni], 0, 0, 0);
    }
  };

  // prologue: stage tile 0
  loadA(0);
  stageB(0, 0);
  writeA(0);
  __syncthreads();

  int buf = 0;
#pragma unroll 1
  for (int tt = 0; tt < 16; ++tt) {
    if (tt + 1 < 16) {
      loadA((tt + 1) * 64);
      stageB(buf ^ 1, (tt + 1) * 64);
    }
    compute(buf);
    if (tt + 1 < 16) writeA(buf ^ 1);
    __syncthreads();
    buf ^= 1;
  }

  // epilogue: add bias, store f32
  const int colg = n0 + wn * 64 + l15;
  float bbv[4];
#pragma unroll
  for (int ni = 0; ni < 4; ++ni) bbv[ni] = bb[colg + ni * 16];
#pragma unroll
  for (int mi = 0; mi < 4; ++mi) {
    const long rbase = m0 + wm * 64 + mi * 16 + lg * 4;
#pragma unroll
    for (int ni = 0; ni < 4; ++ni) {
#pragma unroll
      for (int r = 0; r < 4; ++r)
        emb[(rbase + r) * DEMB + colg + ni * 16] = acc[mi][ni][r] + bbv[ni];
    }
  }
}

// ---------- kernel 2: heads (pooled + selected source), one wave per row ----------
__global__ __launch_bounds__(256) void head_kernel(const float* __restrict__ emb,
                                                   const int* __restrict__ sid,
                                                   const float* __restrict__ Wp,
                                                   const float* __restrict__ bp,
                                                   const float* __restrict__ Ws,
                                                   const float* __restrict__ bs,
                                                   float* __restrict__ out) {
  const int t = threadIdx.x;
  const int lane = t & 63;
  const int w = t >> 6;
  const long row = (long)blockIdx.x * 4 + w;
  const float* e = emb + row * DEMB;
  const int s = sid[row];
  const float2* wp2 = (const float2*)Wp;
  const float2* ws2 = (const float2*)(Ws + (long)s * (DEMB * 2));
  float a0 = 0.f, a1 = 0.f, a2 = 0.f, a3 = 0.f;
#pragma unroll
  for (int j = 0; j < 8; ++j) {
    int c = j * 64 + lane;
    float ev = e[c];
    float2 wp = wp2[c];
    float2 wv = ws2[c];
    a0 = fmaf(ev, wp.x, a0);
    a1 = fmaf(ev, wp.y, a1);
    a2 = fmaf(ev, wv.x, a2);
    a3 = fmaf(ev, wv.y, a3);
  }
#pragma unroll
  for (int m = 32; m >= 1; m >>= 1) {
    a0 += __shfl_xor(a0, m);
    a1 += __shfl_xor(a1, m);
    a2 += __shfl_xor(a2, m);
    a3 += __shfl_xor(a3, m);
  }
  if (lane == 0) {
    float* hp = out + NROWS * DEMB;
    hp[row]             = a0 + bp[0];
    hp[NROWS + row]     = softplusf(a1 + bp[1]) + 0.001f;
    hp[2 * NROWS + row] = a2 + bs[s * 2 + 0];
    hp[3 * NROWS + row] = softplusf(a3 + bs[s * 2 + 1]) + 0.001f;
  }
}

extern "C" void kernel_launch(void* const* d_in, const int* in_sizes, int n_in,
                              void* d_out, int out_size, void* d_ws, size_t ws_size,
                              hipStream_t stream) {
  const float* x  = (const float*)d_in[0];
  const int* sid  = (const int*)d_in[1];
  const float* Wb = (const float*)d_in[2];
  const float* bb = (const float*)d_in[3];
  const float* Wp = (const float*)d_in[4];
  const float* bp = (const float*)d_in[5];
  const float* Ws = (const float*)d_in[6];
  const float* bs = (const float*)d_in[7];
  float* out = (float*)d_out;
  unsigned short* WbT = (unsigned short*)d_ws;   // 512*1024*2 = 1 MiB

  wb_transpose<<<256, 256, 0, stream>>>(Wb, WbT);
  gemm_bias<<<4096, 256, 0, stream>>>(x, WbT, bb, out);
  head_kernel<<<32768, 256, 0, stream>>>(out, sid, Wp, bp, Ws, bs, out);
}